// Round 2
// baseline (296.792 us; speedup 1.0000x reference)
//
#include <hip/hip_runtime.h>

#define LDIM 256
#define PDIM 128
#define NHEAD 4
#define DHEAD 32
#define NPOS (LDIM*LDIM)   // 65536

typedef __attribute__((ext_vector_type(8))) short bf16x8;
typedef __attribute__((ext_vector_type(4))) float f32x4;

static __device__ __forceinline__ unsigned short f2bf(float f) {
  union { float f; unsigned int u; } v; v.f = f;
  unsigned int r = v.u + 0x7fffu + ((v.u >> 16) & 1u);
  return (unsigned short)(r >> 16);
}
static __device__ __forceinline__ float bf2f(unsigned short u) {
  union { unsigned int u; float f; } v; v.u = ((unsigned int)u) << 16;
  return v.f;
}

// ---------------- K0: pack transposed bf16 weights ----------------
// WT[n][k], n in [0,512): 0-127 Wq^T*(1/sqrt(32)), 128-255 Wk^T, 256-383 Wv^T, 384-511 Wg^T
__global__ void k_pack(const float* __restrict__ Wq, const float* __restrict__ Wk,
                       const float* __restrict__ Wv, const float* __restrict__ Wg,
                       const float* __restrict__ Wo,
                       ushort* __restrict__ WT, ushort* __restrict__ WoT) {
  int idx = blockIdx.x * blockDim.x + threadIdx.x;
  if (idx < 512 * 128) {
    int n = idx >> 7, k = idx & 127;
    int nn = n & 127;
    float val;
    if (n < 128)      val = Wq[k * 128 + nn] * 0.17677669529663687f;
    else if (n < 256) val = Wk[k * 128 + nn];
    else if (n < 384) val = Wv[k * 128 + nn];
    else              val = Wg[k * 128 + nn];
    WT[idx] = f2bf(val);
  } else if (idx < 512 * 128 + 128 * 128) {
    int j = idx - 512 * 128;
    int n = j >> 7, k = j & 127;
    WoT[j] = f2bf(Wo[k * 128 + n]);
  }
}

// ---------------- K1: fused LN + bias einsum + QKVG projection ----------------
// block = 64 positions; out: qkvg[pos][512] bf16 (q|k|v|gate), biasg[h][NPOS] f32
__global__ __launch_bounds__(256) void k_ln_proj(
    const float* __restrict__ in, const float* __restrict__ gamma,
    const float* __restrict__ beta, const float* __restrict__ Wb,
    const ushort* __restrict__ WT, const float* __restrict__ bg,
    ushort* __restrict__ qkvg, float* __restrict__ biasg) {
  __shared__ __align__(16) ushort xlds[64 * 136];   // bf16 LN(x) tile, stride 136
  __shared__ __align__(16) ushort stage[64 * 256];  // flat staging tile (no pad)
  int t = threadIdx.x;
  int pos0 = blockIdx.x * 64;
  {
    // ---- LN phase: thread = (row = t>>2, quarter q = t&3), 32 f32 each ----
    int row = t >> 2, q = t & 3;
    const float* rp = in + (size_t)(pos0 + row) * 128 + q * 32;
    float xv[32];
    float s = 0.f, ss = 0.f;
    #pragma unroll
    for (int o = 0; o < 8; o++) {
      float4 v = ((const float4*)rp)[o];
      xv[o*4+0] = v.x; xv[o*4+1] = v.y; xv[o*4+2] = v.z; xv[o*4+3] = v.w;
      s  += v.x + v.y + v.z + v.w;
      ss += v.x*v.x + v.y*v.y + v.z*v.z + v.w*v.w;
    }
    s  += __shfl_xor(s, 1, 64);  s  += __shfl_xor(s, 2, 64);
    ss += __shfl_xor(ss, 1, 64); ss += __shfl_xor(ss, 2, 64);
    float mu  = s * (1.0f / 128.0f);
    float var = ss * (1.0f / 128.0f) - mu * mu;
    float rs  = rsqrtf(var + 1e-5f);
    float p0 = 0.f, p1 = 0.f, p2 = 0.f, p3 = 0.f;
    const float4* gp = (const float4*)(gamma + q * 32);
    const float4* bp = (const float4*)(beta  + q * 32);
    const float4* wbp = (const float4*)(Wb + q * 32 * 4);  // Wb row j = float4
    #pragma unroll
    for (int o = 0; o < 8; o++) {
      float4 g4 = gp[o], b4 = bp[o];
      float xn0 = (xv[o*4+0] - mu) * rs * g4.x + b4.x;
      float xn1 = (xv[o*4+1] - mu) * rs * g4.y + b4.y;
      float xn2 = (xv[o*4+2] - mu) * rs * g4.z + b4.z;
      float xn3 = (xv[o*4+3] - mu) * rs * g4.w + b4.w;
      xv[o*4+0] = xn0; xv[o*4+1] = xn1; xv[o*4+2] = xn2; xv[o*4+3] = xn3;
      float4 w0 = wbp[o*4+0], w1 = wbp[o*4+1], w2 = wbp[o*4+2], w3 = wbp[o*4+3];
      p0 += xn0*w0.x + xn1*w1.x + xn2*w2.x + xn3*w3.x;
      p1 += xn0*w0.y + xn1*w1.y + xn2*w2.y + xn3*w3.y;
      p2 += xn0*w0.z + xn1*w1.z + xn2*w2.z + xn3*w3.z;
      p3 += xn0*w0.w + xn1*w1.w + xn2*w2.w + xn3*w3.w;
    }
    p0 += __shfl_xor(p0, 1, 64); p0 += __shfl_xor(p0, 2, 64);
    p1 += __shfl_xor(p1, 1, 64); p1 += __shfl_xor(p1, 2, 64);
    p2 += __shfl_xor(p2, 1, 64); p2 += __shfl_xor(p2, 2, 64);
    p3 += __shfl_xor(p3, 1, 64); p3 += __shfl_xor(p3, 2, 64);
    if (q == 0) {
      biasg[0 * NPOS + pos0 + row] = p0;
      biasg[1 * NPOS + pos0 + row] = p1;
      biasg[2 * NPOS + pos0 + row] = p2;
      biasg[3 * NPOS + pos0 + row] = p3;
    }
    // pack bf16 -> xlds
    #pragma unroll
    for (int o = 0; o < 4; o++) {
      bf16x8 pk;
      #pragma unroll
      for (int e = 0; e < 8; e++) pk[e] = (short)f2bf(xv[o*8+e]);
      *(bf16x8*)(&xlds[row * 136 + q * 32 + o * 8]) = pk;
    }
  }
  __syncthreads();
  // ---- GEMM phase ----
  int wv = t >> 6, lane = t & 63;
  int n = lane & 15, g = lane >> 4;
  int m0 = wv * 16;
  bf16x8 a[4];
  #pragma unroll
  for (int kc = 0; kc < 4; kc++)
    a[kc] = *(const bf16x8*)(&xlds[(m0 + n) * 136 + kc * 32 + g * 8]);
  float bgv[8];
  #pragma unroll
  for (int j = 0; j < 8; j++) bgv[j] = bg[j * 16 + n];
  #pragma unroll
  for (int sp = 0; sp < 2; sp++) {
    f32x4 acc[16];
    #pragma unroll
    for (int ntl = 0; ntl < 16; ntl++) {
      f32x4 c = {0.f, 0.f, 0.f, 0.f};
      #pragma unroll
      for (int kc = 0; kc < 4; kc++) {
        bf16x8 b = *(const bf16x8*)(WT + (size_t)(sp * 256 + ntl * 16 + n) * 128 + kc * 32 + g * 8);
        c = __builtin_amdgcn_mfma_f32_16x16x32_bf16(a[kc], b, c, 0, 0, 0);
      }
      acc[ntl] = c;
    }
    #pragma unroll
    for (int ntl = 0; ntl < 16; ntl++) {
      #pragma unroll
      for (int r = 0; r < 4; r++) {
        float val = acc[ntl][r];
        if (sp == 1 && ntl >= 8)
          val = 1.0f / (1.0f + __expf(-(val + bgv[ntl - 8])));  // gate sigmoid
        stage[(m0 + g * 4 + r) * 256 + ntl * 16 + n] = f2bf(val);
      }
    }
    __syncthreads();
    // drain: lane-contiguous 16B chunks -> 512B contiguous global segments
    #pragma unroll
    for (int s = 0; s < 8; s++) {
      int chunk = t + 256 * s;
      int row = chunk >> 5, inrow = (chunk & 31) * 8;
      *(bf16x8*)(qkvg + (size_t)(pos0 + row) * 512 + sp * 256 + inrow) =
          *(const bf16x8*)(&stage[chunk * 8]);
    }
    __syncthreads();
  }
}

// ---------------- K2: attention per (i,h) ----------------
#define SV 264
#define SP 264
__global__ __launch_bounds__(256) void k_attn(
    const ushort* __restrict__ qkvg, const float* __restrict__ biasg,
    ushort* __restrict__ gctx) {
  __shared__ __align__(16) ushort VT[32 * SV];       // V^T: [d][kpos]
  __shared__ __align__(16) ushort Psh[4][16 * SP];   // per-wave P tile / ctx stage
  int i = blockIdx.x >> 2;
  int h = blockIdx.x & 3;
  int tid = threadIdx.x, wv = tid >> 6, lane = tid & 63;
  int n = lane & 15, g = lane >> 4;
  const ushort* base = qkvg + (size_t)i * 256 * 512;
  // stage V transposed into LDS (thread t handles key position t)
  {
    const bf16x8* src = (const bf16x8*)(base + (size_t)tid * 512 + 256 + h * 32);
    bf16x8 e0 = src[0], e1 = src[1], e2 = src[2], e3 = src[3];
    #pragma unroll
    for (int d = 0; d < 8; d++) {
      VT[(d)      * SV + tid] = (ushort)e0[d];
      VT[(d + 8)  * SV + tid] = (ushort)e1[d];
      VT[(d + 16) * SV + tid] = (ushort)e2[d];
      VT[(d + 24) * SV + tid] = (ushort)e3[d];
    }
  }
  __syncthreads();
  bf16x8 vf[8][2];
  #pragma unroll
  for (int kc = 0; kc < 8; kc++)
    #pragma unroll
    for (int nt = 0; nt < 2; nt++)
      vf[kc][nt] = *(const bf16x8*)(&VT[(nt * 16 + n) * SV + kc * 32 + g * 8]);

  for (int jj = 0; jj < 4; jj++) {
    int j0 = (wv * 4 + jj) * 16;
    bf16x8 aq = *(const bf16x8*)(base + (size_t)(j0 + n) * 512 + h * 32 + g * 8);
    f32x4 s[16];
    #pragma unroll
    for (int kt = 0; kt < 16; kt++) {
      f32x4 c;
      #pragma unroll
      for (int r = 0; r < 4; r++)
        c[r] = biasg[(size_t)h * NPOS + (size_t)(j0 + g * 4 + r) * 256 + kt * 16 + n];
      bf16x8 bk = *(const bf16x8*)(base + (size_t)(kt * 16 + n) * 512 + 128 + h * 32 + g * 8);
      s[kt] = __builtin_amdgcn_mfma_f32_16x16x32_bf16(aq, bk, c, 0, 0, 0);
    }
    float inv[4];
    #pragma unroll
    for (int r = 0; r < 4; r++) {
      float m = s[0][r];
      #pragma unroll
      for (int kt = 1; kt < 16; kt++) m = fmaxf(m, s[kt][r]);
      #pragma unroll
      for (int xm = 1; xm < 16; xm <<= 1) m = fmaxf(m, __shfl_xor(m, xm, 16));
      float sm = 0.f;
      #pragma unroll
      for (int kt = 0; kt < 16; kt++) {
        float p = __expf(s[kt][r] - m);
        s[kt][r] = p;
        sm += p;
      }
      #pragma unroll
      for (int xm = 1; xm < 16; xm <<= 1) sm += __shfl_xor(sm, xm, 16);
      inv[r] = 1.0f / sm;
    }
    ushort* Pw = Psh[wv];
    #pragma unroll
    for (int kt = 0; kt < 16; kt++)
      #pragma unroll
      for (int r = 0; r < 4; r++)
        Pw[(g * 4 + r) * SP + kt * 16 + n] = f2bf(s[kt][r] * inv[r]);
    __syncthreads();
    f32x4 ctx0 = {0.f, 0.f, 0.f, 0.f}, ctx1 = {0.f, 0.f, 0.f, 0.f};
    #pragma unroll
    for (int kc = 0; kc < 8; kc++) {
      bf16x8 ap = *(const bf16x8*)(&Pw[n * SP + kc * 32 + g * 8]);
      ctx0 = __builtin_amdgcn_mfma_f32_16x16x32_bf16(ap, vf[kc][0], ctx0, 0, 0, 0);
      ctx1 = __builtin_amdgcn_mfma_f32_16x16x32_bf16(ap, vf[kc][1], ctx1, 0, 0, 0);
    }
    // stage ctx f32 into this wave's LDS region (stride 36, 16B-aligned rows)
    float* CT = (float*)Pw;
    #pragma unroll
    for (int r = 0; r < 4; r++) {
      CT[(g * 4 + r) * 36 +      n] = ctx0[r];
      CT[(g * 4 + r) * 36 + 16 + n] = ctx1[r];
    }
    __syncthreads();
    // drain: lane l = (row l>>2, part l&3); 16B gate load, 16B gctx store
    {
      int row = lane >> 2, part = lane & 3;
      int j = j0 + row;
      bf16x8 gt = *(const bf16x8*)(base + (size_t)j * 512 + 384 + h * 32 + part * 8);
      bf16x8 outp;
      #pragma unroll
      for (int e = 0; e < 8; e++) {
        float cv = CT[row * 36 + part * 8 + e];
        outp[e] = (short)f2bf(cv * bf2f((unsigned short)gt[e]));
      }
      *(bf16x8*)(gctx + ((size_t)i * 256 + j) * 128 + h * 32 + part * 8) = outp;
    }
  }
}

// ---------------- K3: output projection + bias + residual ----------------
__global__ __launch_bounds__(256) void k_out(
    const ushort* __restrict__ gctx, const ushort* __restrict__ WoT,
    const float* __restrict__ bo, const float* __restrict__ in0,
    float* __restrict__ out) {
  __shared__ __align__(16) float FT[64 * 128];
  int t = threadIdx.x;
  int wv = t >> 6, lane = t & 63;
  int n = lane & 15, g = lane >> 4;
  int pos0 = blockIdx.x * 64;
  int m0 = wv * 16;
  bf16x8 a[4];
  #pragma unroll
  for (int kc = 0; kc < 4; kc++)
    a[kc] = *(const bf16x8*)(gctx + (size_t)(pos0 + m0 + n) * 128 + kc * 32 + g * 8);
  float bov[8];
  #pragma unroll
  for (int j = 0; j < 8; j++) bov[j] = bo[j * 16 + n];
  #pragma unroll
  for (int nt = 0; nt < 8; nt++) {
    f32x4 acc = {0.f, 0.f, 0.f, 0.f};
    #pragma unroll
    for (int kc = 0; kc < 4; kc++) {
      bf16x8 b = *(const bf16x8*)(WoT + (size_t)(nt * 16 + n) * 128 + kc * 32 + g * 8);
      acc = __builtin_amdgcn_mfma_f32_16x16x32_bf16(a[kc], b, acc, 0, 0, 0);
    }
    #pragma unroll
    for (int r = 0; r < 4; r++)
      FT[(m0 + g * 4 + r) * 128 + nt * 16 + n] = acc[r] + bov[nt];
  }
  __syncthreads();
  const f32x4* inp = (const f32x4*)(in0 + (size_t)pos0 * 128);
  f32x4* outp = (f32x4*)(out + (size_t)pos0 * 128);
  #pragma unroll
  for (int s = 0; s < 8; s++) {
    int idx = t + 256 * s;
    f32x4 v = *(const f32x4*)(&FT[idx * 4]);
    f32x4 r = inp[idx];
    v[0] += r[0]; v[1] += r[1]; v[2] += r[2]; v[3] += r[3];
    outp[idx] = v;
  }
}

extern "C" void kernel_launch(void* const* d_in, const int* in_sizes, int n_in,
                              void* d_out, int out_size, void* d_ws, size_t ws_size,
                              hipStream_t stream) {
  const float* in0   = (const float*)d_in[0];
  const float* gamma = (const float*)d_in[1];
  const float* beta  = (const float*)d_in[2];
  const float* Wq    = (const float*)d_in[3];
  const float* Wk    = (const float*)d_in[4];
  const float* Wv    = (const float*)d_in[5];
  const float* Wb    = (const float*)d_in[6];
  const float* Wg    = (const float*)d_in[7];
  const float* bg    = (const float*)d_in[8];
  const float* Wo    = (const float*)d_in[9];
  const float* bo    = (const float*)d_in[10];
  float* out = (float*)d_out;
  char* ws = (char*)d_ws;

  const size_t MB = 1024 * 1024;
  ushort* qkvg = (ushort*)(ws);              // 64 MB: [pos][512] = q|k|v|gate
  ushort* gctx = (ushort*)(ws + 64 * MB);    // 16 MB: [pos][128]
  float*  bias = (float*) (ws + 80 * MB);    // 1 MB:  [h][NPOS]
  ushort* WT   = (ushort*)(ws + 81 * MB);    // 128 KB
  ushort* WoT  = (ushort*)(ws + 82 * MB);    // 32 KB

  k_pack<<<320, 256, 0, stream>>>(Wq, Wk, Wv, Wg, Wo, WT, WoT);
  k_ln_proj<<<1024, 256, 0, stream>>>(in0, gamma, beta, Wb, WT, bg, qkvg, bias);
  k_attn<<<1024, 256, 0, stream>>>(qkvg, bias, gctx);
  k_out<<<1024, 256, 0, stream>>>(gctx, WoT, bo, in0, out);
}